// Round 12
// baseline (77.379 us; speedup 1.0000x reference)
//
#include <hip/hip_runtime.h>

// LIF SNN, 50 timesteps x 8192 neurons.
// 1) prep:         x f32 -> bf16 (padded to 64 t, vectorized), zero flag
// 2) ff_gemm_mfma: P[ks][t][j] = sum_{k in chunk} x[t][k]*w_in[j][k] via bf16
//                  MFMA. W+A staged by global_load_lds DMA (16B) into a
//                  TRIPLE-buffered, XOR-swizzled LDS tile; counted
//                  s_waitcnt vmcnt(10) + raw s_barrier per step (T3/T4):
//                  next stage's DMA stays in flight across the barrier —
//                  no vmcnt(0) drain in the main loop (r10 residual).
// 3) reduce_ff:    FF = sum of 8 bf16 partial planes (vectorized us8)
// 4) spec_scan:    per-neuron scan assuming no spikes (threshold margin ~15
//                  units); 50 FF values prefetched; flags if any spike
// 5) lif_fallback: exact sequential event-driven scan, runs only if flagged.

#define NEUR 8192
#define TSTEPS 50
#define TPAD 64

typedef __attribute__((ext_vector_type(8))) short bs8;           // 8 bf16
typedef __attribute__((ext_vector_type(4))) float fx4;           // MFMA C/D
typedef __attribute__((ext_vector_type(8))) unsigned short us8;  // 8 bf16 bits

static __device__ __forceinline__ unsigned short f2b(float f) {
    // f32 -> bf16 round-to-nearest-even
    unsigned u = __float_as_uint(f);
    return (unsigned short)((u + 0x7FFFu + ((u >> 16) & 1u)) >> 16);
}
static __device__ __forceinline__ float b2f(unsigned short b) {
    return __uint_as_float(((unsigned)b) << 16);
}

// ---------------- K0: convert x (vectorized), zero flag ----------------
__global__ __launch_bounds__(256)
void prep(const float* __restrict__ x, unsigned short* __restrict__ xb,
          int* __restrict__ flag)
{
    const int e8 = blockIdx.x * 256 + threadIdx.x;   // < TPAD*NEUR/8 = 65536
    const int e  = e8 * 8;
    const int t  = e >> 13;
    us8 o;
    if (t < TSTEPS) {
        const float4 lo = *(const float4*)&x[e];
        const float4 hi = *(const float4*)&x[e + 4];
        o = (us8){f2b(lo.x), f2b(lo.y), f2b(lo.z), f2b(lo.w),
                  f2b(hi.x), f2b(hi.y), f2b(hi.z), f2b(hi.w)};
    } else {
        o = (us8){0, 0, 0, 0, 0, 0, 0, 0};
    }
    *(us8*)&xb[e] = o;
    if (e8 == 0) *flag = 0;
}

// ---------------- K1: feed-forward GEMM, triple-buffered DMA + counted vmcnt ----------------
// grid = 64 j-blocks (128 j) x 8 k-splits = 512; block = 4 waves (1 block/CU,
// LDS 120 KB); 16 steps of BK=64 f32; per step 40 KB DMA (10 instr/wave).
#define KSPLIT 8
#define KCHUNK (NEUR / KSPLIT)   // 1024
#define BK 64
#define NS (KCHUNK / BK)         // 16

__global__ __launch_bounds__(256)
void ff_gemm_mfma(const float* __restrict__ w,            // [8192][8192]
                  const unsigned short* __restrict__ xb,  // [64][8192] bf16 bits
                  unsigned short* __restrict__ P)         // [KSPLIT][50][8192] bf16
{
    // 120 KB LDS: W triple-buffer 3x32 KB + A triple-buffer 3x8 KB
    __shared__ __align__(16) unsigned char Wl[3][32768];
    __shared__ __align__(16) unsigned char Al[3][8192];

    const int tid  = threadIdx.x;
    const int wv   = tid >> 6;
    const int lane = tid & 63;
    const int jb   = blockIdx.x & 63;     // 64 j-blocks
    const int ks   = blockIdx.x >> 6;     // 8 k-splits
    const int j0   = jb * 128;
    const int k0   = ks * KCHUNK;
    const int lrow = lane & 15;           // fragment free-dim index
    const int lgrp = lane >> 4;           // k-group (0..3), 8 k each

    fx4 acc[2][4];
#pragma unroll
    for (int jt = 0; jt < 2; ++jt)
#pragma unroll
        for (int tb = 0; tb < 4; ++tb)
            acc[jt][tb] = (fx4){0.f, 0.f, 0.f, 0.f};

    // --- stage step s into buffer b: linear LDS dest, inverse-XOR'd source ---
    // W: 128 rows x 256 B (64 f32); LDS 16B-slot c holds global chunk c^(r&7).
    // A:  64 rows x 128 B (64 bf16); same involution on 8 chunks/row.
#define STAGE(s, b)                                                           \
    do {                                                                      \
        _Pragma("unroll") for (int it = 0; it < 8; ++it) {                    \
            const int flat = it * 256 + tid;                                  \
            const int r_ = flat >> 4, c_ = flat & 15;                         \
            const char* g_ = (const char*)w +                                 \
                (((size_t)(j0 + r_) * NEUR + k0 + (s) * BK) * 4)              \
                + ((c_ * 16) ^ ((r_ & 7) << 4));                              \
            __builtin_amdgcn_global_load_lds(g_, &Wl[b][it * 4096 + wv * 1024], \
                                             16, 0, 0);                       \
        }                                                                     \
        _Pragma("unroll") for (int it = 0; it < 2; ++it) {                    \
            const int flat = it * 256 + tid;                                  \
            const int r_ = flat >> 3, c_ = flat & 7;                          \
            const char* g_ = (const char*)xb +                                \
                (((size_t)r_ * NEUR + k0 + (s) * BK) * 2)                     \
                + ((c_ * 16) ^ ((r_ & 7) << 4));                              \
            __builtin_amdgcn_global_load_lds(g_, &Al[b][it * 4096 + wv * 1024], \
                                             16, 0, 0);                       \
        }                                                                     \
    } while (0)

    // --- compute one step from buffer b (r10-proven layout) ---
#define COMPUTE(b)                                                            \
    do {                                                                      \
        _Pragma("unroll") for (int k2 = 0; k2 < 2; ++k2) {                    \
            bs8 bf0, bf1;                                                     \
            {                                                                 \
                const int rj = wv * 32 + lrow;                                \
                const int sw = (rj & 7) << 4;                                 \
                const int g0 = k2 * 8 + lgrp * 2;                             \
                const float4 lo = *(const float4*)&Wl[b][rj * 256 + ((g0 * 16) ^ sw)];        \
                const float4 hi = *(const float4*)&Wl[b][rj * 256 + (((g0 + 1) * 16) ^ sw)];  \
                bf0 = (bs8){(short)f2b(lo.x), (short)f2b(lo.y), (short)f2b(lo.z),             \
                            (short)f2b(lo.w), (short)f2b(hi.x), (short)f2b(hi.y),             \
                            (short)f2b(hi.z), (short)f2b(hi.w)};              \
            }                                                                 \
            {                                                                 \
                const int rj = wv * 32 + 16 + lrow;                           \
                const int sw = (rj & 7) << 4;                                 \
                const int g0 = k2 * 8 + lgrp * 2;                             \
                const float4 lo = *(const float4*)&Wl[b][rj * 256 + ((g0 * 16) ^ sw)];        \
                const float4 hi = *(const float4*)&Wl[b][rj * 256 + (((g0 + 1) * 16) ^ sw)];  \
                bf1 = (bs8){(short)f2b(lo.x), (short)f2b(lo.y), (short)f2b(lo.z),             \
                            (short)f2b(lo.w), (short)f2b(hi.x), (short)f2b(hi.y),             \
                            (short)f2b(hi.z), (short)f2b(hi.w)};              \
            }                                                                 \
            _Pragma("unroll") for (int tb = 0; tb < 4; ++tb) {                \
                const int rt = tb * 16 + lrow;                                \
                const bs8 a_ = *(const bs8*)&Al[b][rt * 128 +                 \
                    (((k2 * 4 + lgrp) * 16) ^ ((rt & 7) << 4))];              \
                acc[0][tb] = __builtin_amdgcn_mfma_f32_16x16x32_bf16(a_, bf0, acc[0][tb], 0, 0, 0); \
                acc[1][tb] = __builtin_amdgcn_mfma_f32_16x16x32_bf16(a_, bf1, acc[1][tb], 0, 0, 0); \
            }                                                                 \
        }                                                                     \
    } while (0)

    // prologue: two stages in flight
    STAGE(0, 0);
    STAGE(1, 1);

#pragma unroll 1
    for (int s = 0; s < NS - 1; ++s) {
        const int bc = s % 3;
        // stage s complete (oldest 10 ops), stage s+1 stays IN FLIGHT
        asm volatile("s_waitcnt vmcnt(10)" ::: "memory");
        __builtin_amdgcn_sched_barrier(0);
        __builtin_amdgcn_s_barrier();       // all waves' stage-s DMA visible;
                                            // also seals reads of buf[(s+2)%3]
        if (s + 2 < NS) STAGE(s + 2, (s + 2) % 3);
        COMPUTE(bc);
    }
    // peeled last step: full drain only here
    asm volatile("s_waitcnt vmcnt(0)" ::: "memory");
    __builtin_amdgcn_sched_barrier(0);
    __builtin_amdgcn_s_barrier();
    COMPUTE((NS - 1) % 3);
#undef STAGE
#undef COMPUTE

    // epilogue: C/D layout col = lane&15 (-> j), row = (lane>>4)*4 + reg (-> t)
#pragma unroll
    for (int jt = 0; jt < 2; ++jt) {
        const int j = j0 + wv * 32 + jt * 16 + lrow;
#pragma unroll
        for (int tb = 0; tb < 4; ++tb)
#pragma unroll
            for (int i = 0; i < 4; ++i) {
                const int t = tb * 16 + lgrp * 4 + i;
                if (t < TSTEPS)
                    P[((size_t)ks * TSTEPS + t) * NEUR + j] = f2b(acc[jt][tb][i]);
            }
    }
}

// ---------------- K2: reduce bf16 partials -> FF f32 ----------------
__global__ __launch_bounds__(256)
void reduce_ff(const unsigned short* __restrict__ P, float* __restrict__ FF)
{
    const int i = (blockIdx.x * 256 + threadIdx.x) * 8;   // 200 blocks
    float s[8];
#pragma unroll
    for (int n = 0; n < 8; ++n) s[n] = 0.f;
#pragma unroll
    for (int ks = 0; ks < KSPLIT; ++ks) {
        const us8 p = *(const us8*)&P[(size_t)ks * TSTEPS * NEUR + i];
#pragma unroll
        for (int n = 0; n < 8; ++n) s[n] += b2f(p[n]);
    }
    *(float4*)&FF[i]     = make_float4(s[0], s[1], s[2], s[3]);
    *(float4*)&FF[i + 4] = make_float4(s[4], s[5], s[6], s[7]);
}

// ---------------- K3: speculative parallel scan (assumes z == 0) ----------------
__global__ __launch_bounds__(256)
void spec_scan(const float* __restrict__ FF, float* __restrict__ out,
               int* __restrict__ flag)
{
    const int j = blockIdx.x * 256 + threadIdx.x;   // one neuron per thread
    float ff[TSTEPS];                               // full prefetch, static idx
#pragma unroll
    for (int t = 0; t < TSTEPS; ++t) ff[t] = FF[(size_t)t * NEUR + j];

    float v = -70.f, cur = 0.f;
    bool any = false;
#pragma unroll
    for (int t = 0; t < TSTEPS; ++t) {
        const float vd = v + 5.0e-5f * ((-70.f - v) + cur);
        const float id = cur - 1.0e-4f * cur;
        const bool sp = vd > -55.f;
        any |= sp;
        v = sp ? -70.f : vd;
        cur = id + ff[t];                           // no recurrence (speculation)
        out[(size_t)t * NEUR + j] = sp ? 1.f : 0.f;
    }
    if (any) atomicAdd(flag, 1);
}

// ---------------- K4: exact event-driven fallback (only if spikes occurred) ----------------
__global__ __launch_bounds__(1024)
void lif_fallback(const float* __restrict__ FF, const float* __restrict__ wrec,
                  float* __restrict__ out, const int* __restrict__ flag)
{
    if (*flag == 0) return;   // speculation was self-consistent -> out is exact

    const int tid = threadIdx.x;
    __shared__ unsigned short list[2][NEUR];
    __shared__ int cnt[2];

    float v[8], cur[8];
#pragma unroll
    for (int n = 0; n < 8; ++n) { v[n] = -70.0f; cur[n] = 0.0f; }
    if (tid == 0) { cnt[0] = 0; cnt[1] = 0; }

    for (int t = 0; t < TSTEPS; ++t) {
        const int rb = t & 1, wb = rb ^ 1;
        __syncthreads();
        if (tid == 0) cnt[wb] = 0;
        __syncthreads();

        float rec[8];
#pragma unroll
        for (int n = 0; n < 8; ++n) rec[n] = 0.0f;
        const int c = cnt[rb];
        for (int s = 0; s < c; ++s) {
            const int k = list[rb][s];
#pragma unroll
            for (int n = 0; n < 8; ++n)
                rec[n] += wrec[(size_t)(tid + n * 1024) * NEUR + k];
        }

#pragma unroll
        for (int n = 0; n < 8; ++n) {
            const float ff = FF[(size_t)t * NEUR + tid + n * 1024];
            const float vd = v[n] + 5.0e-5f * ((-70.0f - v[n]) + cur[n]);
            const float id = cur[n] - 1.0e-4f * cur[n];
            const bool  sp = vd > -55.0f;
            v[n]   = sp ? -70.0f : vd;
            cur[n] = id + ff + rec[n];
            out[(size_t)t * NEUR + tid + n * 1024] = sp ? 1.0f : 0.0f;
            if (sp) {
                const int pos = atomicAdd(&cnt[wb], 1);
                list[wb][pos] = (unsigned short)(tid + n * 1024);
            }
        }
    }
}

extern "C" void kernel_launch(void* const* d_in, const int* in_sizes, int n_in,
                              void* d_out, int out_size, void* d_ws, size_t ws_size,
                              hipStream_t stream) {
    const float* x     = (const float*)d_in[0];   // [50][8192]
    const float* w_in  = (const float*)d_in[1];   // [8192][8192]
    const float* w_rec = (const float*)d_in[2];   // [8192][8192]
    float* out = (float*)d_out;

    // ws layout (16B-aligned):
    //   FF  f32  [50][8192]          1,638,400 B  @ 0
    //   xb  bf16 [64][8192]          1,048,576 B  @ 1,638,400
    //   P   bf16 [8][50][8192]       6,553,600 B  @ 2,686,976
    //   flag int                             4 B  @ 9,240,576
    float* FF          = (float*)d_ws;
    unsigned short* xb = (unsigned short*)((char*)d_ws + 1638400);
    unsigned short* P  = (unsigned short*)((char*)d_ws + 2686976);
    int* flag          = (int*)((char*)d_ws + 9240576);

    prep        <<<dim3(TPAD * NEUR / 8 / 256),   dim3(256),  0, stream>>>(x, xb, flag);
    ff_gemm_mfma<<<dim3(64 * KSPLIT),             dim3(256),  0, stream>>>(w_in, xb, P);
    reduce_ff   <<<dim3(TSTEPS * NEUR / 8 / 256), dim3(256),  0, stream>>>(P, FF);
    spec_scan   <<<dim3(NEUR / 256),              dim3(256),  0, stream>>>(FF, out, flag);
    lif_fallback<<<dim3(1),                       dim3(1024), 0, stream>>>(FF, w_rec, out, flag);
}

// Round 13
// 59.337 us; speedup vs baseline: 1.3041x; 1.3041x over previous
//
#include <hip/hip_runtime.h>

// LIF SNN, 50 timesteps x 8192 neurons.  [r10 structure — proven 59.4 us]
// 1) prep:         x f32 -> bf16 (padded to 64 t, vectorized), zero flag
// 2) ff_gemm_mfma: P[ks][t][j] = sum_{k in chunk} x[t][k]*w_in[j][k] via bf16
//                  MFMA. W+A staged by global_load_lds DMA (16B) into a
//                  double-buffered, XOR-swizzled LDS tile; linear LDS dest +
//                  inverse-XOR global source + XOR ds_read (rule #21); one
//                  __syncthreads per K-step; 2 blocks/CU stagger their DMA so
//                  HBM stays busy across each block's barrier drain.
// 3) reduce_ff:    FF = sum of 8 bf16 partial planes (vectorized us8)
// 4) spec_scan:    per-neuron scan assuming no spikes (threshold margin ~15
//                  units); 50 FF values prefetched; flags if any spike
// 5) lif_fallback: exact sequential event-driven scan, runs only if flagged.

#define NEUR 8192
#define TSTEPS 50
#define TPAD 64

typedef __attribute__((ext_vector_type(8))) short bs8;           // 8 bf16
typedef __attribute__((ext_vector_type(4))) float fx4;           // MFMA C/D
typedef __attribute__((ext_vector_type(8))) unsigned short us8;  // 8 bf16 bits

static __device__ __forceinline__ unsigned short f2b(float f) {
    // f32 -> bf16 round-to-nearest-even
    unsigned u = __float_as_uint(f);
    return (unsigned short)((u + 0x7FFFu + ((u >> 16) & 1u)) >> 16);
}
static __device__ __forceinline__ float b2f(unsigned short b) {
    return __uint_as_float(((unsigned)b) << 16);
}

// ---------------- K0: convert x (vectorized), zero flag ----------------
__global__ __launch_bounds__(256)
void prep(const float* __restrict__ x, unsigned short* __restrict__ xb,
          int* __restrict__ flag)
{
    const int e8 = blockIdx.x * 256 + threadIdx.x;   // < TPAD*NEUR/8 = 65536
    const int e  = e8 * 8;
    const int t  = e >> 13;
    us8 o;
    if (t < TSTEPS) {
        const float4 lo = *(const float4*)&x[e];
        const float4 hi = *(const float4*)&x[e + 4];
        o = (us8){f2b(lo.x), f2b(lo.y), f2b(lo.z), f2b(lo.w),
                  f2b(hi.x), f2b(hi.y), f2b(hi.z), f2b(hi.w)};
    } else {
        o = (us8){0, 0, 0, 0, 0, 0, 0, 0};
    }
    *(us8*)&xb[e] = o;
    if (e8 == 0) *flag = 0;
}

// ---------------- K1: feed-forward GEMM, global_load_lds staged ----------------
// grid = 64 j-blocks (128 j) x 8 k-splits = 512 (2 resident blocks/CU);
// block = 4 waves; 16 steps of BK=64 f32; W tile 32 KB + A tile 8 KB per step.
#define KSPLIT 8
#define KCHUNK (NEUR / KSPLIT)   // 1024
#define BK 64
#define NS (KCHUNK / BK)         // 16

__global__ __launch_bounds__(256)
void ff_gemm_mfma(const float* __restrict__ w,            // [8192][8192]
                  const unsigned short* __restrict__ xb,  // [64][8192] bf16 bits
                  unsigned short* __restrict__ P)         // [KSPLIT][50][8192] bf16
{
    // 80 KB LDS: W double-buffer 2x32 KB + A double-buffer 2x8 KB
    __shared__ __align__(16) unsigned char Wl[2][32768];
    __shared__ __align__(16) unsigned char Al[2][8192];

    const int tid  = threadIdx.x;
    const int wv   = tid >> 6;
    const int lane = tid & 63;
    const int jb   = blockIdx.x & 63;     // 64 j-blocks
    const int ks   = blockIdx.x >> 6;     // 8 k-splits
    const int j0   = jb * 128;
    const int k0   = ks * KCHUNK;
    const int lrow = lane & 15;           // fragment free-dim index
    const int lgrp = lane >> 4;           // k-group (0..3), 8 k each

    fx4 acc[2][4];
#pragma unroll
    for (int jt = 0; jt < 2; ++jt)
#pragma unroll
        for (int tb = 0; tb < 4; ++tb)
            acc[jt][tb] = (fx4){0.f, 0.f, 0.f, 0.f};

    // --- stage step s into buffer b: linear LDS dest, inverse-XOR'd source ---
    // W: 128 rows x 256 B (64 f32); LDS 16B-slot c holds global chunk c^(r&7).
    // A:  64 rows x 128 B (64 bf16); same involution on 8 chunks/row.
#define STAGE(s, b)                                                           \
    do {                                                                      \
        _Pragma("unroll") for (int it = 0; it < 8; ++it) {                    \
            const int flat = it * 256 + tid;                                  \
            const int r_ = flat >> 4, c_ = flat & 15;                         \
            const char* g_ = (const char*)w +                                 \
                (((size_t)(j0 + r_) * NEUR + k0 + (s) * BK) * 4)              \
                + ((c_ * 16) ^ ((r_ & 7) << 4));                              \
            __builtin_amdgcn_global_load_lds(g_, &Wl[b][it * 4096 + wv * 1024], \
                                             16, 0, 0);                       \
        }                                                                     \
        _Pragma("unroll") for (int it = 0; it < 2; ++it) {                    \
            const int flat = it * 256 + tid;                                  \
            const int r_ = flat >> 3, c_ = flat & 7;                          \
            const char* g_ = (const char*)xb +                                \
                (((size_t)r_ * NEUR + k0 + (s) * BK) * 2)                     \
                + ((c_ * 16) ^ ((r_ & 7) << 4));                              \
            __builtin_amdgcn_global_load_lds(g_, &Al[b][it * 4096 + wv * 1024], \
                                             16, 0, 0);                       \
        }                                                                     \
    } while (0)

    // --- compute one step from buffer b: 2 k-subs x (2 B-frags + 4 A-frags) ---
#define COMPUTE(b)                                                            \
    do {                                                                      \
        _Pragma("unroll") for (int k2 = 0; k2 < 2; ++k2) {                    \
            bs8 bf0, bf1;                                                     \
            {                                                                 \
                const int rj = wv * 32 + lrow;                                \
                const int sw = (rj & 7) << 4;                                 \
                const int g0 = k2 * 8 + lgrp * 2;                             \
                const float4 lo = *(const float4*)&Wl[b][rj * 256 + ((g0 * 16) ^ sw)];        \
                const float4 hi = *(const float4*)&Wl[b][rj * 256 + (((g0 + 1) * 16) ^ sw)];  \
                bf0 = (bs8){(short)f2b(lo.x), (short)f2b(lo.y), (short)f2b(lo.z),             \
                            (short)f2b(lo.w), (short)f2b(hi.x), (short)f2b(hi.y),             \
                            (short)f2b(hi.z), (short)f2b(hi.w)};              \
            }                                                                 \
            {                                                                 \
                const int rj = wv * 32 + 16 + lrow;                           \
                const int sw = (rj & 7) << 4;                                 \
                const int g0 = k2 * 8 + lgrp * 2;                             \
                const float4 lo = *(const float4*)&Wl[b][rj * 256 + ((g0 * 16) ^ sw)];        \
                const float4 hi = *(const float4*)&Wl[b][rj * 256 + (((g0 + 1) * 16) ^ sw)];  \
                bf1 = (bs8){(short)f2b(lo.x), (short)f2b(lo.y), (short)f2b(lo.z),             \
                            (short)f2b(lo.w), (short)f2b(hi.x), (short)f2b(hi.y),             \
                            (short)f2b(hi.z), (short)f2b(hi.w)};              \
            }                                                                 \
            _Pragma("unroll") for (int tb = 0; tb < 4; ++tb) {                \
                const int rt = tb * 16 + lrow;                                \
                const bs8 a_ = *(const bs8*)&Al[b][rt * 128 +                 \
                    (((k2 * 4 + lgrp) * 16) ^ ((rt & 7) << 4))];              \
                acc[0][tb] = __builtin_amdgcn_mfma_f32_16x16x32_bf16(a_, bf0, acc[0][tb], 0, 0, 0); \
                acc[1][tb] = __builtin_amdgcn_mfma_f32_16x16x32_bf16(a_, bf1, acc[1][tb], 0, 0, 0); \
            }                                                                 \
        }                                                                     \
    } while (0)

    STAGE(0, 0);
    __syncthreads();                       // prologue drain: buf0 ready

#pragma unroll 1
    for (int s = 0; s < NS; s += 2) {
        if (s + 1 < NS) STAGE(s + 1, 1);   // DMA next step while computing
        COMPUTE(0);
        __syncthreads();                   // drain: buf1 ready, buf0 consumed
        if (s + 2 < NS) STAGE(s + 2, 0);
        COMPUTE(1);
        __syncthreads();                   // drain: buf0 ready, buf1 consumed
    }
#undef STAGE
#undef COMPUTE

    // epilogue: C/D layout col = lane&15 (-> j), row = (lane>>4)*4 + reg (-> t)
#pragma unroll
    for (int jt = 0; jt < 2; ++jt) {
        const int j = j0 + wv * 32 + jt * 16 + lrow;
#pragma unroll
        for (int tb = 0; tb < 4; ++tb)
#pragma unroll
            for (int i = 0; i < 4; ++i) {
                const int t = tb * 16 + lgrp * 4 + i;
                if (t < TSTEPS)
                    P[((size_t)ks * TSTEPS + t) * NEUR + j] = f2b(acc[jt][tb][i]);
            }
    }
}

// ---------------- K2: reduce bf16 partials -> FF f32 ----------------
__global__ __launch_bounds__(256)
void reduce_ff(const unsigned short* __restrict__ P, float* __restrict__ FF)
{
    const int i = (blockIdx.x * 256 + threadIdx.x) * 8;   // 200 blocks
    float s[8];
#pragma unroll
    for (int n = 0; n < 8; ++n) s[n] = 0.f;
#pragma unroll
    for (int ks = 0; ks < KSPLIT; ++ks) {
        const us8 p = *(const us8*)&P[(size_t)ks * TSTEPS * NEUR + i];
#pragma unroll
        for (int n = 0; n < 8; ++n) s[n] += b2f(p[n]);
    }
    *(float4*)&FF[i]     = make_float4(s[0], s[1], s[2], s[3]);
    *(float4*)&FF[i + 4] = make_float4(s[4], s[5], s[6], s[7]);
}

// ---------------- K3: speculative parallel scan (assumes z == 0) ----------------
__global__ __launch_bounds__(256)
void spec_scan(const float* __restrict__ FF, float* __restrict__ out,
               int* __restrict__ flag)
{
    const int j = blockIdx.x * 256 + threadIdx.x;   // one neuron per thread
    float ff[TSTEPS];                               // full prefetch, static idx
#pragma unroll
    for (int t = 0; t < TSTEPS; ++t) ff[t] = FF[(size_t)t * NEUR + j];

    float v = -70.f, cur = 0.f;
    bool any = false;
#pragma unroll
    for (int t = 0; t < TSTEPS; ++t) {
        const float vd = v + 5.0e-5f * ((-70.f - v) + cur);
        const float id = cur - 1.0e-4f * cur;
        const bool sp = vd > -55.f;
        any |= sp;
        v = sp ? -70.f : vd;
        cur = id + ff[t];                           // no recurrence (speculation)
        out[(size_t)t * NEUR + j] = sp ? 1.f : 0.f;
    }
    if (any) atomicAdd(flag, 1);
}

// ---------------- K4: exact event-driven fallback (only if spikes occurred) ----------------
__global__ __launch_bounds__(1024)
void lif_fallback(const float* __restrict__ FF, const float* __restrict__ wrec,
                  float* __restrict__ out, const int* __restrict__ flag)
{
    if (*flag == 0) return;   // speculation was self-consistent -> out is exact

    const int tid = threadIdx.x;
    __shared__ unsigned short list[2][NEUR];
    __shared__ int cnt[2];

    float v[8], cur[8];
#pragma unroll
    for (int n = 0; n < 8; ++n) { v[n] = -70.0f; cur[n] = 0.0f; }
    if (tid == 0) { cnt[0] = 0; cnt[1] = 0; }

    for (int t = 0; t < TSTEPS; ++t) {
        const int rb = t & 1, wb = rb ^ 1;
        __syncthreads();
        if (tid == 0) cnt[wb] = 0;
        __syncthreads();

        float rec[8];
#pragma unroll
        for (int n = 0; n < 8; ++n) rec[n] = 0.0f;
        const int c = cnt[rb];
        for (int s = 0; s < c; ++s) {
            const int k = list[rb][s];
#pragma unroll
            for (int n = 0; n < 8; ++n)
                rec[n] += wrec[(size_t)(tid + n * 1024) * NEUR + k];
        }

#pragma unroll
        for (int n = 0; n < 8; ++n) {
            const float ff = FF[(size_t)t * NEUR + tid + n * 1024];
            const float vd = v[n] + 5.0e-5f * ((-70.0f - v[n]) + cur[n]);
            const float id = cur[n] - 1.0e-4f * cur[n];
            const bool  sp = vd > -55.0f;
            v[n]   = sp ? -70.0f : vd;
            cur[n] = id + ff + rec[n];
            out[(size_t)t * NEUR + tid + n * 1024] = sp ? 1.0f : 0.0f;
            if (sp) {
                const int pos = atomicAdd(&cnt[wb], 1);
                list[wb][pos] = (unsigned short)(tid + n * 1024);
            }
        }
    }
}

extern "C" void kernel_launch(void* const* d_in, const int* in_sizes, int n_in,
                              void* d_out, int out_size, void* d_ws, size_t ws_size,
                              hipStream_t stream) {
    const float* x     = (const float*)d_in[0];   // [50][8192]
    const float* w_in  = (const float*)d_in[1];   // [8192][8192]
    const float* w_rec = (const float*)d_in[2];   // [8192][8192]
    float* out = (float*)d_out;

    // ws layout (16B-aligned):
    //   FF  f32  [50][8192]          1,638,400 B  @ 0
    //   xb  bf16 [64][8192]          1,048,576 B  @ 1,638,400
    //   P   bf16 [8][50][8192]       6,553,600 B  @ 2,686,976
    //   flag int                             4 B  @ 9,240,576
    float* FF          = (float*)d_ws;
    unsigned short* xb = (unsigned short*)((char*)d_ws + 1638400);
    unsigned short* P  = (unsigned short*)((char*)d_ws + 2686976);
    int* flag          = (int*)((char*)d_ws + 9240576);

    prep        <<<dim3(TPAD * NEUR / 8 / 256),   dim3(256),  0, stream>>>(x, xb, flag);
    ff_gemm_mfma<<<dim3(64 * KSPLIT),             dim3(256),  0, stream>>>(w_in, xb, P);
    reduce_ff   <<<dim3(TSTEPS * NEUR / 8 / 256), dim3(256),  0, stream>>>(P, FF);
    spec_scan   <<<dim3(NEUR / 256),              dim3(256),  0, stream>>>(FF, out, flag);
    lif_fallback<<<dim3(1),                       dim3(1024), 0, stream>>>(FF, w_rec, out, flag);
}